// Round 4
// baseline (368.747 us; speedup 1.0000x reference)
//
#include <hip/hip_runtime.h>

// MSE between pred_iou[32,8] and binary-Jaccard IoU from pred_masks
// [32,8,512,512] fp32 (>0.5) vs target_masks [32,512,512] int32 (>0).
//
// R4: n-major LINEAR streaming. Each block reads ONE contiguous 128 KB span
// of ONE pred mask (single linear stream, like the 6.7 TB/s harness fill)
// plus the matching 128 KB tgt span. tgt is logically read 8x (once per n)
// but the 8 reader blocks have blockIdx stride 8 -> same XCD (%8 round-robin)
// -> L2 hit; worst case the 32 MB tgt lives in the 256 MB L3. Pred loads are
// non-temporal (read-once); tgt loads cached. HBM floor: 256+32 MB ~ 46 us.

#define BS      32
#define NMASKS  8
#define HW      (512 * 512)            // 262144 elems per mask
#define GROUPS  8                      // spans per (b,n) mask
#define SPAN    (HW / GROUPS)          // 32768 elems = 128 KB
#define BLOCK   256
#define NPAIRS  (BS * NMASKS)          // 256
#define PER_THREAD (SPAN / (BLOCK * 4))  // 32 vec4 iters per thread

typedef int   iv4 __attribute__((ext_vector_type(4)));
typedef float fv4 __attribute__((ext_vector_type(4)));

__global__ __launch_bounds__(BLOCK, 8) void iou_count_kernel(
    const int* __restrict__ tgt,
    const float* __restrict__ pred,
    unsigned long long* __restrict__ ws)
{
    // blockIdx = b*64 + n*8 + grp. grp in LOW bits: the 8 blocks sharing a
    // tgt span (same b,grp; n=0..7) are blockIdx stride 8 -> same XCD.
    const int idx = blockIdx.x;
    const int b   = idx >> 6;
    const int n   = (idx >> 3) & 7;
    const int grp = idx & 7;
    const int tid = threadIdx.x;

    const size_t tgt_base  = (size_t)b * HW + (size_t)grp * SPAN;
    const size_t pred_base = ((size_t)b * NMASKS + n) * HW + (size_t)grp * SPAN;

    unsigned int inter = 0u, uni = 0u;

#pragma unroll 4
    for (int it = 0; it < PER_THREAD; ++it) {
        const size_t off = (size_t)it * (BLOCK * 4) + (size_t)tid * 4;

        const iv4 t4 = *(const iv4*)(tgt + tgt_base + off);                 // cached (reused by 8 n's)
        const fv4 p4 = __builtin_nontemporal_load(
            (const fv4*)(pred + pred_base + off));                          // streaming

        const int tb0 = t4.x > 0, tb1 = t4.y > 0, tb2 = t4.z > 0, tb3 = t4.w > 0;
        const int pb0 = p4.x > 0.5f, pb1 = p4.y > 0.5f,
                  pb2 = p4.z > 0.5f, pb3 = p4.w > 0.5f;

        inter += (unsigned)((pb0 & tb0) + (pb1 & tb1) + (pb2 & tb2) + (pb3 & tb3));
        uni   += (unsigned)((pb0 | tb0) + (pb1 | tb1) + (pb2 | tb2) + (pb3 | tb3));
    }

    // pack (inter,union) in one u64 (counts <= 262144: no cross-field carry)
    unsigned long long v =
        ((unsigned long long)inter << 32) | (unsigned long long)uni;

    const int lane = tid & 63;
    const int wave = tid >> 6;
    __shared__ unsigned long long s[BLOCK / 64];

#pragma unroll
    for (int off = 32; off > 0; off >>= 1)
        v += __shfl_down(v, off);
    if (lane == 0) s[wave] = v;
    __syncthreads();

    // one u64 partial per block -> unique slot; no zeroing of ws needed.
    if (tid == 0)
        ws[(size_t)grp * NPAIRS + (size_t)b * NMASKS + n] =
            s[0] + s[1] + s[2] + s[3];
}

__global__ __launch_bounds__(NPAIRS) void finalize_kernel(
    const float* __restrict__ pred_iou,
    const unsigned long long* __restrict__ ws,
    float* __restrict__ out)
{
    const int i = threadIdx.x;   // pair index 0..255; coalesced per group row
    unsigned long long v = 0ull;
#pragma unroll
    for (int g = 0; g < GROUPS; ++g)
        v += ws[(size_t)g * NPAIRS + i];

    const unsigned int inter = (unsigned int)(v >> 32);
    const unsigned int uni   = (unsigned int)(v & 0xffffffffu);
    // reference: where(union>0, inter/max(union,1), 0); union>=1 when >0
    const float iou = (uni > 0u) ? ((float)inter / (float)uni) : 0.0f;
    const float d = pred_iou[i] - iou;
    out[i] = d * d;
}

extern "C" void kernel_launch(void* const* d_in, const int* in_sizes, int n_in,
                              void* d_out, int out_size, void* d_ws, size_t ws_size,
                              hipStream_t stream) {
    const float* pred_iou = (const float*)d_in[0];          // [32,8]
    const int*   tgt      = (const int*)d_in[1];            // [32,512,512]
    const float* pred     = (const float*)d_in[2];          // [32,8,512,512]
    float* out = (float*)d_out;
    unsigned long long* ws = (unsigned long long*)d_ws;     // 8*256 u64 = 16 KB

    iou_count_kernel<<<BS * NMASKS * GROUPS, BLOCK, 0, stream>>>(tgt, pred, ws);
    finalize_kernel<<<1, NPAIRS, 0, stream>>>(pred_iou, ws, out);
}

// Round 5
// 367.299 us; speedup vs baseline: 1.0039x; 1.0039x over previous
//
#include <hip/hip_runtime.h>

// MSE between pred_iou[32,8] and binary-Jaccard IoU from pred_masks
// [32,8,512,512] fp32 (>0.5) vs target_masks [32,512,512] int32 (>0).
//
// R5: ballot-bitmask two-phase.
//  Phase 1: tgt (32 MB) -> wave ballots, 1 bit/elem, layout bm[window*4+j] =
//           __ballot(tgt[window*256 + lane*4 + j] > 0). 1 MB total, lives in
//           L2/L3 across the dispatch boundary.
//  Phase 2: each block = ONE contiguous 128 KB linear nt stream of ONE pred
//           mask (2048 streams device-wide, zero over-fetch). Per wave-iter:
//           1 KB pred + one wave-uniform 32 B bitmask read; counting is
//           popcount(ballot(p>0.5) & w) -> mostly SALU.
// HBM floor: 256 MB pred + 32 MB tgt + ~2 MB bitmask ~ 46 us at 6.3 TB/s.

#define BS      32
#define NMASKS  8
#define HW      (512 * 512)              // 262144 elems per mask
#define WPI     (HW / 256)               // 1024 windows per image
#define TOTAL_W (BS * WPI)               // 32768 windows
#define GROUPS  8                        // spans per (b,n) mask
#define SPAN    (HW / GROUPS)            // 32768 elems = 128 KB
#define BLOCK   256
#define NPAIRS  (BS * NMASKS)            // 256
#define ITERS   (SPAN / (BLOCK * 4))     // 32 float4-iters per thread

typedef int   iv4 __attribute__((ext_vector_type(4)));
typedef float fv4 __attribute__((ext_vector_type(4)));

// ---- phase 1: build ballot bitmask (32 MB -> 1 MB) ----
__global__ __launch_bounds__(BLOCK) void build_bitmask(
    const int* __restrict__ tgt,
    unsigned long long* __restrict__ bm)
{
    const int lane  = threadIdx.x & 63;
    const int gwave = blockIdx.x * (BLOCK / 64) + (threadIdx.x >> 6); // 0..1023
    const int w0    = gwave * (TOTAL_W / 1024);                       // 32 windows/wave

#pragma unroll 4
    for (int i = 0; i < TOTAL_W / 1024; ++i) {
        const int w = w0 + i;
        const iv4 t4 = __builtin_nontemporal_load(
            (const iv4*)(tgt + (size_t)w * 256 + (size_t)lane * 4));
        const unsigned long long b0 = __ballot(t4.x > 0);
        const unsigned long long b1 = __ballot(t4.y > 0);
        const unsigned long long b2 = __ballot(t4.z > 0);
        const unsigned long long b3 = __ballot(t4.w > 0);
        if (lane == 0) {
            unsigned long long* p = bm + (size_t)w * 4;
            p[0] = b0; p[1] = b1; p[2] = b2; p[3] = b3;
        }
    }
}

// ---- phase 2: linear pred streams + ballot counting ----
__global__ __launch_bounds__(BLOCK, 8) void iou_count_kernel(
    const float* __restrict__ pred,
    const unsigned long long* __restrict__ bm,
    unsigned long long* __restrict__ ws)
{
    // blockIdx = b*64 + n*8 + grp
    const int idx = blockIdx.x;
    const int b   = idx >> 6;
    const int n   = (idx >> 3) & 7;
    const int grp = idx & 7;
    const int tid = threadIdx.x;
    const int wv  = tid >> 6;

    const float* pbase =
        pred + ((size_t)(b * NMASKS + n)) * HW + (size_t)grp * SPAN + (size_t)tid * 4;

    // window index for this wave at it=0; advances by 4 per iter.
    // readfirstlane -> wave-uniform so the 32 B bitmask read can scalarize.
    const int wbase = __builtin_amdgcn_readfirstlane(
        b * WPI + grp * (SPAN / 256) + wv);

    unsigned int inter = 0u, uni = 0u;

#pragma unroll 4
    for (int it = 0; it < ITERS; ++it) {
        const fv4 p4 = __builtin_nontemporal_load(
            (const fv4*)(pbase + (size_t)it * (BLOCK * 4)));

        const unsigned long long* wp = bm + (size_t)(wbase + it * 4) * 4;
        const unsigned long long w0 = wp[0], w1 = wp[1], w2 = wp[2], w3 = wp[3];

        const unsigned long long p0 = __ballot(p4.x > 0.5f);
        const unsigned long long p1 = __ballot(p4.y > 0.5f);
        const unsigned long long p2 = __ballot(p4.z > 0.5f);
        const unsigned long long p3 = __ballot(p4.w > 0.5f);

        inter += (unsigned)(__popcll(p0 & w0) + __popcll(p1 & w1) +
                            __popcll(p2 & w2) + __popcll(p3 & w3));
        uni   += (unsigned)(__popcll(p0 | w0) + __popcll(p1 | w1) +
                            __popcll(p2 | w2) + __popcll(p3 | w3));
    }

    // per-wave scalars -> LDS -> one u64 partial per block (counts <= 8192
    // per wave, <= 32768 per block: no cross-field carry in the pack).
    __shared__ unsigned long long s[BLOCK / 64];
    if ((tid & 63) == 0)
        s[wv] = ((unsigned long long)inter << 32) | (unsigned long long)uni;
    __syncthreads();

    if (tid == 0)
        ws[(size_t)grp * NPAIRS + (size_t)b * NMASKS + n] =
            s[0] + s[1] + s[2] + s[3];
}

__global__ __launch_bounds__(NPAIRS) void finalize_kernel(
    const float* __restrict__ pred_iou,
    const unsigned long long* __restrict__ ws,
    float* __restrict__ out)
{
    const int i = threadIdx.x;   // pair 0..255
    unsigned long long v = 0ull;
#pragma unroll
    for (int g = 0; g < GROUPS; ++g)
        v += ws[(size_t)g * NPAIRS + i];

    const unsigned int inter = (unsigned int)(v >> 32);
    const unsigned int uni   = (unsigned int)(v & 0xffffffffu);
    // reference: where(union>0, inter/max(union,1), 0); union>=1 when >0
    const float iou = (uni > 0u) ? ((float)inter / (float)uni) : 0.0f;
    const float d = pred_iou[i] - iou;
    out[i] = d * d;
}

extern "C" void kernel_launch(void* const* d_in, const int* in_sizes, int n_in,
                              void* d_out, int out_size, void* d_ws, size_t ws_size,
                              hipStream_t stream) {
    const float* pred_iou = (const float*)d_in[0];          // [32,8]
    const int*   tgt      = (const int*)d_in[1];            // [32,512,512]
    const float* pred     = (const float*)d_in[2];          // [32,8,512,512]
    float* out = (float*)d_out;

    // ws layout: [0,16KB) block partials; [64KB,64KB+1MB) bitmask.
    unsigned long long* partials = (unsigned long long*)d_ws;
    unsigned long long* bm = (unsigned long long*)((char*)d_ws + (64 << 10));

    build_bitmask<<<1024 / (BLOCK / 64), BLOCK, 0, stream>>>(tgt, bm);
    iou_count_kernel<<<BS * NMASKS * GROUPS, BLOCK, 0, stream>>>(pred, bm, partials);
    finalize_kernel<<<1, NPAIRS, 0, stream>>>(pred_iou, partials, out);
}